// Round 11
// baseline (162.200 us; speedup 1.0000x reference)
//
#include <hip/hip_runtime.h>
#include <hip/hip_bf16.h>

#define NH    12
#define HD    64
#define NTOK  1024
#define BATCH 8
#define DM    768

typedef short  short8  __attribute__((ext_vector_type(8)));
typedef float  f32x4   __attribute__((ext_vector_type(4)));
typedef float  f32x16  __attribute__((ext_vector_type(16)));
typedef unsigned short ushort8 __attribute__((ext_vector_type(8)));

// sqrt(0.125 * log2(e)) — pre-scales vn so QK^T yields CS*cos directly
#define SQRT_CS 0.42466056f

__device__ __forceinline__ ushort f2bf(float f) {
    union { float f; unsigned u; } x; x.f = f;
    unsigned r = x.u + 0x7FFF + ((x.u >> 16) & 1);   // RNE
    return (ushort)(r >> 16);
}
__device__ __forceinline__ float bf2f(ushort h) {
    union { unsigned u; float f; } x; x.u = ((unsigned)h) << 16;
    return x.f;
}
__device__ __forceinline__ void gl_lds16(const ushort* g, ushort* l) {
    __builtin_amdgcn_global_load_lds(
        (const __attribute__((address_space(1))) unsigned int*)g,
        (__attribute__((address_space(3))) unsigned int*)l, 16, 0, 0);
}
__device__ __forceinline__ f32x16 mfma32(short8 a, short8 b, f32x16 c) {
    return __builtin_amdgcn_mfma_f32_32x32x16_bf16(a, b, c, 0, 0, 0);
}

// ---------------------------------------------------------------------------
// Split kernels: x -> (hi, lo) bf16 with hi = bf16(x), lo = bf16(x - hi).
// q is also transposed [n][b][d] -> [b][n][d] so GEMM tile rows are contiguous.
// ---------------------------------------------------------------------------
__global__ __launch_bounds__(256) void split_q_kernel(
    const float* __restrict__ src, ushort* __restrict__ hi, ushort* __restrict__ lo)
{
    int t = blockIdx.x * 256 + threadIdx.x;       // 786432 threads, 8 elems each
    int dblk = t % 96; int nb = t / 96; int b = nb & 7; int n = nb >> 3;
    const float* s = src + (size_t)t * 8;
    size_t o = ((size_t)(b * 1024 + n) * 96 + dblk) * 8;
    float4 x0 = *(const float4*)s, x1 = *(const float4*)(s + 4);
    float xs[8] = {x0.x, x0.y, x0.z, x0.w, x1.x, x1.y, x1.z, x1.w};
    ushort8 h8, l8;
    #pragma unroll
    for (int j = 0; j < 8; ++j) {
        ushort h = f2bf(xs[j]);
        h8[j] = h;
        l8[j] = f2bf(xs[j] - bf2f(h));
    }
    *(ushort8*)(hi + o) = h8;
    *(ushort8*)(lo + o) = l8;
}

__global__ __launch_bounds__(256) void split_w_kernel(
    const float* __restrict__ src, ushort* __restrict__ hi, ushort* __restrict__ lo)
{
    int t = blockIdx.x * 256 + threadIdx.x;       // 73728 threads
    const float* s = src + (size_t)t * 8;
    float4 x0 = *(const float4*)s, x1 = *(const float4*)(s + 4);
    float xs[8] = {x0.x, x0.y, x0.z, x0.w, x1.x, x1.y, x1.z, x1.w};
    ushort8 h8, l8;
    #pragma unroll
    for (int j = 0; j < 8; ++j) {
        ushort h = f2bf(xs[j]);
        h8[j] = h;
        l8[j] = f2bf(xs[j] - bf2f(h));
    }
    size_t o = (size_t)t * 8;
    *(ushort8*)(hi + o) = h8;
    *(ushort8*)(lo + o) = l8;
}

// ---------------------------------------------------------------------------
// vproj via split-bf16 MFMA: C = Ah.Bh + Ah.Bl + Al.Bh  (fp32 accum).
// 128x128 tile (2 heads), BK=64, 4 waves 2x2 (each 64x64), 32x32x16 MFMA.
// XCD-swizzled 1D grid. Epilogue pre-scales vn by SQRT_CS (softmax folding).
// (unchanged — 806 TF ≈ 90% of the 2-phase structural ceiling)
// ---------------------------------------------------------------------------
__global__ __launch_bounds__(256) void vproj_mfma_kernel(
    const ushort* __restrict__ qh, const ushort* __restrict__ ql,
    const ushort* __restrict__ wh, const ushort* __restrict__ wl,
    ushort* __restrict__ vn, ushort* __restrict__ vt)
{
    __shared__ __align__(16) char smem[128 * 132 * 4];   // 67584 B
    ushort* Ah = (ushort*)smem;                  // [128][64] swizzled
    ushort* Al = (ushort*)(smem + 16384);
    ushort* Bh = (ushort*)(smem + 32768);
    ushort* Bl = (ushort*)(smem + 49152);

    const int bid = blockIdx.x;                  // 0..383
    const int xcd = bid & 7, s = bid >> 3;       // s 0..47
    const int nb  = s % 6, mbl = s / 6;          // nb 0..5, mbl 0..7
    const int mb  = xcd * 8 + mbl;               // 0..63
    const int m0  = mb * 128;
    const int n0  = nb * 128;

    const int tid = threadIdx.x, wv = tid >> 6, l = tid & 63;
    const int ln  = l & 31, half = l >> 5;
    const int wr  = wv >> 1, wc = wv & 1;

    const ushort* gsrc = (wv == 0) ? qh : (wv == 1) ? ql : (wv == 2) ? wh : wl;
    ushort* ltile = (wv == 0) ? Ah : (wv == 1) ? Al : (wv == 2) ? Bh : Bl;
    const int srow0 = (wv < 2) ? m0 : n0;

    f32x16 acc[2][2] = {};

    for (int kt = 0; kt < 12; ++kt) {
        __syncthreads();                          // prev ds_reads done
        #pragma unroll
        for (int p = 0; p < 16; ++p) {
            int chunk = p * 64 + l;               // 0..1023
            int r = chunk >> 3, c = chunk & 7;
            int csrc = c ^ (r & 7);               // inverse-swizzled source
            gl_lds16(gsrc + (size_t)(srow0 + r) * 768 + kt * 64 + csrc * 8,
                     ltile + p * 512);            // linear LDS dest
        }
        __syncthreads();                          // vmcnt(0) drained here

        #pragma unroll
        for (int ks = 0; ks < 4; ++ks) {
            const int cc = ks * 2 + half;         // k-chunk: k = cc*8 + j
            short8 a_h[2], a_l[2], b_h[2], b_l[2];
            #pragma unroll
            for (int mi = 0; mi < 2; ++mi) {
                int ra = wr * 64 + mi * 32 + ln;
                int so = (cc ^ (ra & 7)) * 8;
                a_h[mi] = *(const short8*)(Ah + ra * 64 + so);
                a_l[mi] = *(const short8*)(Al + ra * 64 + so);
                int rb = wc * 64 + mi * 32 + ln;
                int sb = (cc ^ (rb & 7)) * 8;
                b_h[mi] = *(const short8*)(Bh + rb * 64 + sb);
                b_l[mi] = *(const short8*)(Bl + rb * 64 + sb);
            }
            #pragma unroll
            for (int mi = 0; mi < 2; ++mi)
                #pragma unroll
                for (int ni = 0; ni < 2; ++ni) {
                    acc[mi][ni] = mfma32(a_h[mi], b_h[ni], acc[mi][ni]);
                    acc[mi][ni] = mfma32(a_h[mi], b_l[ni], acc[mi][ni]);
                    acc[mi][ni] = mfma32(a_l[mi], b_h[ni], acc[mi][ni]);
                }
        }
    }

    // ---- epilogue: C tile -> LDS [128][132] f32, norms, vn + vt ----
    __syncthreads();
    float* Ct = (float*)smem;
    #pragma unroll
    for (int mi = 0; mi < 2; ++mi)
        #pragma unroll
        for (int ni = 0; ni < 2; ++ni)
            #pragma unroll
            for (int i = 0; i < 16; ++i) {
                int row = wr * 64 + mi * 32 + (i & 3) + 8 * (i >> 2) + 4 * half;
                Ct[row * 132 + wc * 64 + ni * 32 + ln] = acc[mi][ni][i];
            }
    __syncthreads();

    const int b   = mb >> 3;
    const int nr0 = (mb & 7) * 128;
    {   // vn: thread t -> (row r = t>>1, head-half hh = t&1), 64 cols in-lane
        int r = tid >> 1, hh = tid & 1;
        const float* src = Ct + r * 132 + hh * 64;
        float ss = 0.f;
        #pragma unroll
        for (int j = 0; j < 16; ++j) {
            float4 v4 = *(const float4*)(src + j * 4);
            ss += v4.x * v4.x + v4.y * v4.y + v4.z * v4.z + v4.w * v4.w;
        }
        float rn = rsqrtf(ss) * SQRT_CS;          // fold softmax scale into vn
        int bhn = b * NH + nb * 2 + hh;
        ushort* dst = vn + ((size_t)bhn * NTOK + nr0 + r) * HD;
        #pragma unroll
        for (int q8 = 0; q8 < 8; ++q8) {
            float4 u0 = *(const float4*)(src + q8 * 8);
            float4 u1 = *(const float4*)(src + q8 * 8 + 4);
            ushort8 o;
            o[0] = f2bf(u0.x * rn); o[1] = f2bf(u0.y * rn);
            o[2] = f2bf(u0.z * rn); o[3] = f2bf(u0.w * rn);
            o[4] = f2bf(u1.x * rn); o[5] = f2bf(u1.y * rn);
            o[6] = f2bf(u1.z * rn); o[7] = f2bf(u1.w * rn);
            *(ushort8*)(dst + q8 * 8) = o;
        }
    }
    {   // vt: thread t -> (col d = t&127, 64-row segment seg = t>>7)
        int d = tid & 127, seg = tid >> 7;
        int bhn = b * NH + nb * 2 + (d >> 6);
        int dd = d & 63;
        ushort* dst = vt + ((size_t)bhn * HD + dd) * NTOK + nr0 + seg * 64;
        #pragma unroll
        for (int q8 = 0; q8 < 8; ++q8) {
            ushort8 o;
            #pragma unroll
            for (int j = 0; j < 8; ++j)
                o[j] = f2bf(Ct[(seg * 64 + q8 * 8 + j) * 132 + d]);
            *(ushort8*)(dst + q8 * 8) = o;
        }
    }
}

// ---------------------------------------------------------------------------
// Fallback fp32 vproj (used only if ws_size can't hold the split arrays).
// ---------------------------------------------------------------------------
__global__ __launch_bounds__(256) void vproj_fp32_kernel(
    const float* __restrict__ q, const float* __restrict__ w,
    ushort* __restrict__ vn, ushort* __restrict__ vt)
{
    __shared__ __align__(16) char smem[2 * 32 * 65 * 4];
    float (*As)[65] = (float (*)[65])smem;
    float (*Bs)[65] = (float (*)[65])(smem + 32 * 65 * 4);
    const int h = blockIdx.x, mb = blockIdx.y;
    const int tid = threadIdx.x;
    const int tx = tid & 15, ty = tid >> 4;
    const int m0 = mb * 64, b = m0 >> 10;
    const int lk = tid & 31, lr = tid >> 5;
    float acc[4][4] = {};
    for (int kt = 0; kt < DM; kt += 32) {
        #pragma unroll
        for (int p = 0; p < 8; ++p) {
            int row = lr + p * 8;
            int n = (m0 + row) & (NTOK - 1);
            As[lk][row] = q[(size_t)(n * BATCH + b) * DM + kt + lk];
            Bs[lk][row] = w[(size_t)(h * HD + row) * DM + kt + lk];
        }
        __syncthreads();
        #pragma unroll 8
        for (int k = 0; k < 32; ++k) {
            float a0 = As[k][4*ty+0], a1 = As[k][4*ty+1];
            float a2 = As[k][4*ty+2], a3 = As[k][4*ty+3];
            float b0 = Bs[k][4*tx+0], b1 = Bs[k][4*tx+1];
            float b2 = Bs[k][4*tx+2], b3 = Bs[k][4*tx+3];
            acc[0][0]+=a0*b0; acc[0][1]+=a0*b1; acc[0][2]+=a0*b2; acc[0][3]+=a0*b3;
            acc[1][0]+=a1*b0; acc[1][1]+=a1*b1; acc[1][2]+=a1*b2; acc[1][3]+=a1*b3;
            acc[2][0]+=a2*b0; acc[2][1]+=a2*b1; acc[2][2]+=a2*b2; acc[2][3]+=a2*b3;
            acc[3][0]+=a3*b0; acc[3][1]+=a3*b1; acc[3][2]+=a3*b2; acc[3][3]+=a3*b3;
        }
        __syncthreads();
    }
    const int bh = b * NH + h;
    const int n0 = m0 & (NTOK - 1);
    #pragma unroll
    for (int i = 0; i < 4; ++i) {
        float ss = acc[i][0]*acc[i][0] + acc[i][1]*acc[i][1]
                 + acc[i][2]*acc[i][2] + acc[i][3]*acc[i][3];
        #pragma unroll
        for (int msk = 1; msk < 16; msk <<= 1) ss += __shfl_xor(ss, msk, 16);
        float rn = rsqrtf(ss) * SQRT_CS;
        int n = n0 + 4*ty + i;
        ushort4 o;
        o.x = f2bf(acc[i][0]*rn); o.y = f2bf(acc[i][1]*rn);
        o.z = f2bf(acc[i][2]*rn); o.w = f2bf(acc[i][3]*rn);
        *(ushort4*)&vn[((size_t)bh * NTOK + n) * HD + 4*tx] = o;
    }
    ushort (*T)[72] = (ushort (*)[72])smem;
    #pragma unroll
    for (int i = 0; i < 4; ++i)
        #pragma unroll
        for (int j = 0; j < 4; ++j)
            T[4*tx + j][4*ty + i] = f2bf(acc[i][j]);
    __syncthreads();
    {
        int d = tid >> 2, c = tid & 3;
        uint4 lo = *(const uint4*)&T[d][c*16];
        uint4 hi = *(const uint4*)&T[d][c*16 + 8];
        size_t go = ((size_t)bh * HD + d) * NTOK + n0 + c*16;
        *(uint4*)&vt[go]     = lo;
        *(uint4*)&vt[go + 8] = hi;
    }
}

// ---------------------------------------------------------------------------
// Kernel 2: flash attention — 2-wave blocks (128 thr), Q-tile 64, kv-tile 64.
// 1536 blocks = 6 independent barrier-domains/CU (12 waves/CU) so per-tile
// barriers/serial chains are filled by other blocks' waves. Single-buffered
// K/V LDS (16 KB), T14 reg-hold prefetch, 2 cheap barriers/tile.
// Per-wave arithmetic identical to round 10 (bit-identical output).
// XCD decode: all 16 q-blocks of a bh share bid%8 (KV pinned to one L2).
// ---------------------------------------------------------------------------
__global__ __launch_bounds__(128, 3) void attn_kernel(
    const ushort* __restrict__ vn, const ushort* __restrict__ vt,
    float* __restrict__ out)
{
    __shared__ __align__(16) ushort Klds[64 * 64];   // [kv][d], swizzled
    __shared__ __align__(16) ushort Vlds[64 * 64];   // [d][kv], swizzled
    const int sblk = blockIdx.x;                 // 0..1535
    const int tt   = sblk >> 3;                  // 0..191
    const int bh   = (sblk & 7) + 8 * (tt >> 4);
    const int q0   = (tt & 15) * 64;
    const int tid = threadIdx.x;                 // 0..127
    const int wv  = tid >> 6;                    // 0..1
    const int l   = tid & 63;
    const int ql  = l & 31;          // q column (one q-row per lane)
    const int h   = l >> 5;          // half

    const ushort* vb  = vn + (size_t)bh * NTOK * HD;
    const ushort* vtb = vt + (size_t)bh * HD * NTOK;

    short8 qB[4];
    {
        int qrow = q0 + wv * 32 + ql;
        #pragma unroll
        for (int ks = 0; ks < 4; ++ks)
            qB[ks] = *(const short8*)(vb + (size_t)qrow * HD + ks * 16 + h * 8);
    }

    // staging: thread covers rows sr+16p (p=0..3), col chunk sc, for K and V
    const int sr = tid >> 3;                     // 0..15
    const int sc = tid & 7;
    uint4 kreg[4], vreg[4];

    f32x16 oT[2] = {};
    float l_acc = 0.f;

    // prologue: tile 0 -> regs -> LDS
    #pragma unroll
    for (int p = 0; p < 4; ++p) {
        int r = sr + p * 16;
        kreg[p] = *(const uint4*)(vb + (size_t)r * HD + sc * 8);
        vreg[p] = *(const uint4*)(vtb + (size_t)r * NTOK + sc * 8);
    }
    #pragma unroll
    for (int p = 0; p < 4; ++p) {
        int r = sr + p * 16;
        int slt = (sc ^ (r & 7)) * 8;
        *(uint4*)(Klds + r * 64 + slt) = kreg[p];
        *(uint4*)(Vlds + r * 64 + slt) = vreg[p];
    }
    __syncthreads();

    for (int kt = 0; kt < NTOK / 64; ++kt) {
        // T14: issue next tile's global loads early (land during compute)
        if (kt < NTOK / 64 - 1) {
            int kb = (kt + 1) * 64;
            #pragma unroll
            for (int p = 0; p < 4; ++p) {
                int r = sr + p * 16;
                kreg[p] = *(const uint4*)(vb + (size_t)(kb + r) * HD + sc * 8);
                vreg[p] = *(const uint4*)(vtb + (size_t)r * NTOK + kb + sc * 8);
            }
        }

        f32x16 st[2] = {};
        __builtin_amdgcn_s_setprio(1);
        #pragma unroll
        for (int ks = 0; ks < 4; ++ks) {
            int so = ((2 * ks + h) ^ (ql & 7)) * 8;
            short8 k0 = *(const short8*)(Klds + ql * 64 + so);
            short8 k1 = *(const short8*)(Klds + (32 + ql) * 64 + so);
            st[0] = mfma32(k0, qB[ks], st[0]);
            st[1] = mfma32(k1, qB[ks], st[1]);
        }
        __builtin_amdgcn_s_setprio(0);

        // bounded softmax: p = exp2(s) directly (scale folded into vn)
        #pragma unroll
        for (int g = 0; g < 2; ++g)
            #pragma unroll
            for (int i = 0; i < 16; ++i)
                st[g][i] = __builtin_amdgcn_exp2f(st[g][i]);

        float ts[16];
        #pragma unroll
        for (int i = 0; i < 16; ++i) ts[i] = st[0][i] + st[1][i];
        #pragma unroll
        for (int s = 8; s >= 1; s >>= 1)
            #pragma unroll
            for (int i = 0; i < s; ++i) ts[i] += ts[i + s];
        l_acc += ts[0];

        unsigned pb2[2][4][2];
        #pragma unroll
        for (int g = 0; g < 2; ++g)
            #pragma unroll
            for (int t = 0; t < 4; ++t)
                #pragma unroll
                for (int u = 0; u < 2; ++u)
                    asm("v_cvt_pk_bf16_f32 %0, %1, %2"
                        : "=v"(pb2[g][t][u])
                        : "v"(st[g][4 * t + 2 * u]), "v"(st[g][4 * t + 2 * u + 1]));

        __builtin_amdgcn_s_setprio(1);
        #pragma unroll
        for (int s = 0; s < 4; ++s) {
            const int g = s >> 1, sp = s & 1;
            unsigned x0 = pb2[g][2 * sp][0], y0 = pb2[g][2 * sp + 1][0];
            unsigned x1 = pb2[g][2 * sp][1], y1 = pb2[g][2 * sp + 1][1];
            asm volatile("v_permlane32_swap_b32 %0, %1" : "+v"(x0), "+v"(y0));
            asm volatile("v_permlane32_swap_b32 %0, %1" : "+v"(x1), "+v"(y1));
            union { unsigned u[4]; short8 s8; } pb;
            pb.u[0] = x0; pb.u[1] = x1; pb.u[2] = y0; pb.u[3] = y1;
            int so = ((2 * s + h) ^ (ql & 7)) * 8;
            short8 v0 = *(const short8*)(Vlds + ql * 64 + so);
            short8 v1 = *(const short8*)(Vlds + (32 + ql) * 64 + so);
            oT[0] = mfma32(v0, pb.s8, oT[0]);
            oT[1] = mfma32(v1, pb.s8, oT[1]);
        }
        __builtin_amdgcn_s_setprio(0);

        __syncthreads();                         // both waves done reading
        if (kt < NTOK / 64 - 1) {
            #pragma unroll
            for (int p = 0; p < 4; ++p) {
                int r = sr + p * 16;
                int slt = (sc ^ (r & 7)) * 8;
                *(uint4*)(Klds + r * 64 + slt) = kreg[p];
                *(uint4*)(Vlds + r * 64 + slt) = vreg[p];
            }
            __syncthreads();                     // writes visible
        }
    }

    // epilogue: out[n][b][hh*64+d] = O^T[d][q] / l
    const int b = bh / NH, hh = bh % NH;
    float lsum = l_acc + __shfl_xor(l_acc, 32);
    const float inv = 1.f / lsum;
    int n = q0 + wv * 32 + ql;
    float* orow = out + ((size_t)n * BATCH + b) * DM + hh * HD;
    #pragma unroll
    for (int dm = 0; dm < 2; ++dm)
        #pragma unroll
        for (int t = 0; t < 4; ++t) {
            float4 val = make_float4(oT[dm][4 * t] * inv, oT[dm][4 * t + 1] * inv,
                                     oT[dm][4 * t + 2] * inv, oT[dm][4 * t + 3] * inv);
            *(float4*)(orow + dm * 32 + t * 8 + h * 4) = val;
        }
}

extern "C" void kernel_launch(void* const* d_in, const int* in_sizes, int n_in,
                              void* d_out, int out_size, void* d_ws, size_t ws_size,
                              hipStream_t stream) {
    const float* q = (const float*)d_in[0];   // [1024, 8, 768]
    const float* w = (const float*)d_in[1];   // [768, 768]
    float* out = (float*)d_out;               // [1024, 8, 768]

    const size_t QE = (size_t)NTOK * BATCH * DM;     // 6,291,456
    const size_t WE = (size_t)DM * DM;               //   589,824
    const size_t VE = (size_t)NH * BATCH * NTOK * HD;// 6,291,456

    ushort* vn = (ushort*)d_ws;
    ushort* vt = vn + VE;
    size_t need = (2 * VE + 2 * QE + 2 * WE) * sizeof(ushort);

    if (ws_size >= need) {
        ushort* qh = vt + VE;
        ushort* ql = qh + QE;
        ushort* wh = ql + QE;
        ushort* wl = wh + WE;
        split_q_kernel<<<(QE / 8 + 255) / 256, 256, 0, stream>>>(q, qh, ql);
        split_w_kernel<<<(WE / 8 + 255) / 256, 256, 0, stream>>>(w, wh, wl);
        vproj_mfma_kernel<<<384, 256, 0, stream>>>(qh, ql, wh, wl, vn, vt);
    } else {
        vproj_fp32_kernel<<<dim3(NH, (BATCH * NTOK) / 64), 256, 0, stream>>>(q, w, vn, vt);
    }
    attn_kernel<<<16 * BATCH * NH, 128, 0, stream>>>(vn, vt, out);
}

// Round 12
// 92.418 us; speedup vs baseline: 1.7551x; 1.7551x over previous
//
#include <hip/hip_runtime.h>
#include <hip/hip_bf16.h>

#define NH    12
#define HD    64
#define NTOK  1024
#define BATCH 8
#define DM    768

typedef short  short8  __attribute__((ext_vector_type(8)));
typedef float  f32x4   __attribute__((ext_vector_type(4)));
typedef float  f32x16  __attribute__((ext_vector_type(16)));
typedef unsigned short ushort8 __attribute__((ext_vector_type(8)));

// sqrt(0.125 * log2(e)) — pre-scales vn so QK^T yields CS*cos directly
#define SQRT_CS 0.42466056f

__device__ __forceinline__ ushort f2bf(float f) {
    union { float f; unsigned u; } x; x.f = f;
    unsigned r = x.u + 0x7FFF + ((x.u >> 16) & 1);   // RNE
    return (ushort)(r >> 16);
}
__device__ __forceinline__ float bf2f(ushort h) {
    union { unsigned u; float f; } x; x.u = ((unsigned)h) << 16;
    return x.f;
}
__device__ __forceinline__ void gl_lds16(const ushort* g, ushort* l) {
    __builtin_amdgcn_global_load_lds(
        (const __attribute__((address_space(1))) unsigned int*)g,
        (__attribute__((address_space(3))) unsigned int*)l, 16, 0, 0);
}
__device__ __forceinline__ f32x16 mfma32(short8 a, short8 b, f32x16 c) {
    return __builtin_amdgcn_mfma_f32_32x32x16_bf16(a, b, c, 0, 0, 0);
}

// ---------------------------------------------------------------------------
// Merged split kernel: x -> (hi, lo) bf16, for q (with [n][b][d]->[b][n][d]
// transpose) and w, in one launch.
// ---------------------------------------------------------------------------
__global__ __launch_bounds__(256) void split_qw_kernel(
    const float* __restrict__ qsrc, const float* __restrict__ wsrc,
    ushort* __restrict__ qhi, ushort* __restrict__ qlo,
    ushort* __restrict__ whi, ushort* __restrict__ wlo)
{
    const int NQ = (NTOK * BATCH * DM) / 8;       // 786432
    int t = blockIdx.x * 256 + threadIdx.x;
    const float* s;
    ushort *dh, *dl;
    size_t o;
    if (t < NQ) {
        int dblk = t % 96; int nb = t / 96; int b = nb & 7; int n = nb >> 3;
        s = qsrc + (size_t)t * 8;
        o = ((size_t)(b * 1024 + n) * 96 + dblk) * 8;
        dh = qhi; dl = qlo;
    } else {
        int tw = t - NQ;
        if (tw >= (DM * DM) / 8) return;
        s = wsrc + (size_t)tw * 8;
        o = (size_t)tw * 8;
        dh = whi; dl = wlo;
    }
    float4 x0 = *(const float4*)s, x1 = *(const float4*)(s + 4);
    float xs[8] = {x0.x, x0.y, x0.z, x0.w, x1.x, x1.y, x1.z, x1.w};
    ushort8 h8, l8;
    #pragma unroll
    for (int j = 0; j < 8; ++j) {
        ushort h = f2bf(xs[j]);
        h8[j] = h;
        l8[j] = f2bf(xs[j] - bf2f(h));
    }
    *(ushort8*)(dh + o) = h8;
    *(ushort8*)(dl + o) = l8;
}

// ---------------------------------------------------------------------------
// vproj via split-bf16 MFMA: C = Ah.Bh + Ah.Bl + Al.Bh  (fp32 accum).
// 128x128 tile (2 heads), BK=64, 4 waves 2x2 (each 64x64), 32x32x16 MFMA.
// XCD-swizzled 1D grid. Epilogue pre-scales vn by SQRT_CS (softmax folding).
// (unchanged — 806 TF ≈ 90% of the 2-phase structural ceiling)
// ---------------------------------------------------------------------------
__global__ __launch_bounds__(256) void vproj_mfma_kernel(
    const ushort* __restrict__ qh, const ushort* __restrict__ ql,
    const ushort* __restrict__ wh, const ushort* __restrict__ wl,
    ushort* __restrict__ vn, ushort* __restrict__ vt)
{
    __shared__ __align__(16) char smem[128 * 132 * 4];   // 67584 B
    ushort* Ah = (ushort*)smem;                  // [128][64] swizzled
    ushort* Al = (ushort*)(smem + 16384);
    ushort* Bh = (ushort*)(smem + 32768);
    ushort* Bl = (ushort*)(smem + 49152);

    const int bid = blockIdx.x;                  // 0..383
    const int xcd = bid & 7, s = bid >> 3;       // s 0..47
    const int nb  = s % 6, mbl = s / 6;          // nb 0..5, mbl 0..7
    const int mb  = xcd * 8 + mbl;               // 0..63
    const int m0  = mb * 128;
    const int n0  = nb * 128;

    const int tid = threadIdx.x, wv = tid >> 6, l = tid & 63;
    const int ln  = l & 31, half = l >> 5;
    const int wr  = wv >> 1, wc = wv & 1;

    const ushort* gsrc = (wv == 0) ? qh : (wv == 1) ? ql : (wv == 2) ? wh : wl;
    ushort* ltile = (wv == 0) ? Ah : (wv == 1) ? Al : (wv == 2) ? Bh : Bl;
    const int srow0 = (wv < 2) ? m0 : n0;

    f32x16 acc[2][2] = {};

    for (int kt = 0; kt < 12; ++kt) {
        __syncthreads();                          // prev ds_reads done
        #pragma unroll
        for (int p = 0; p < 16; ++p) {
            int chunk = p * 64 + l;               // 0..1023
            int r = chunk >> 3, c = chunk & 7;
            int csrc = c ^ (r & 7);               // inverse-swizzled source
            gl_lds16(gsrc + (size_t)(srow0 + r) * 768 + kt * 64 + csrc * 8,
                     ltile + p * 512);            // linear LDS dest
        }
        __syncthreads();                          // vmcnt(0) drained here

        #pragma unroll
        for (int ks = 0; ks < 4; ++ks) {
            const int cc = ks * 2 + half;         // k-chunk: k = cc*8 + j
            short8 a_h[2], a_l[2], b_h[2], b_l[2];
            #pragma unroll
            for (int mi = 0; mi < 2; ++mi) {
                int ra = wr * 64 + mi * 32 + ln;
                int so = (cc ^ (ra & 7)) * 8;
                a_h[mi] = *(const short8*)(Ah + ra * 64 + so);
                a_l[mi] = *(const short8*)(Al + ra * 64 + so);
                int rb = wc * 64 + mi * 32 + ln;
                int sb = (cc ^ (rb & 7)) * 8;
                b_h[mi] = *(const short8*)(Bh + rb * 64 + sb);
                b_l[mi] = *(const short8*)(Bl + rb * 64 + sb);
            }
            #pragma unroll
            for (int mi = 0; mi < 2; ++mi)
                #pragma unroll
                for (int ni = 0; ni < 2; ++ni) {
                    acc[mi][ni] = mfma32(a_h[mi], b_h[ni], acc[mi][ni]);
                    acc[mi][ni] = mfma32(a_h[mi], b_l[ni], acc[mi][ni]);
                    acc[mi][ni] = mfma32(a_l[mi], b_h[ni], acc[mi][ni]);
                }
        }
    }

    // ---- epilogue: C tile -> LDS [128][132] f32, norms, vn + vt ----
    __syncthreads();
    float* Ct = (float*)smem;
    #pragma unroll
    for (int mi = 0; mi < 2; ++mi)
        #pragma unroll
        for (int ni = 0; ni < 2; ++ni)
            #pragma unroll
            for (int i = 0; i < 16; ++i) {
                int row = wr * 64 + mi * 32 + (i & 3) + 8 * (i >> 2) + 4 * half;
                Ct[row * 132 + wc * 64 + ni * 32 + ln] = acc[mi][ni][i];
            }
    __syncthreads();

    const int b   = mb >> 3;
    const int nr0 = (mb & 7) * 128;
    {   // vn: thread t -> (row r = t>>1, head-half hh = t&1), 64 cols in-lane
        int r = tid >> 1, hh = tid & 1;
        const float* src = Ct + r * 132 + hh * 64;
        float ss = 0.f;
        #pragma unroll
        for (int j = 0; j < 16; ++j) {
            float4 v4 = *(const float4*)(src + j * 4);
            ss += v4.x * v4.x + v4.y * v4.y + v4.z * v4.z + v4.w * v4.w;
        }
        float rn = rsqrtf(ss) * SQRT_CS;          // fold softmax scale into vn
        int bhn = b * NH + nb * 2 + hh;
        ushort* dst = vn + ((size_t)bhn * NTOK + nr0 + r) * HD;
        #pragma unroll
        for (int q8 = 0; q8 < 8; ++q8) {
            float4 u0 = *(const float4*)(src + q8 * 8);
            float4 u1 = *(const float4*)(src + q8 * 8 + 4);
            ushort8 o;
            o[0] = f2bf(u0.x * rn); o[1] = f2bf(u0.y * rn);
            o[2] = f2bf(u0.z * rn); o[3] = f2bf(u0.w * rn);
            o[4] = f2bf(u1.x * rn); o[5] = f2bf(u1.y * rn);
            o[6] = f2bf(u1.z * rn); o[7] = f2bf(u1.w * rn);
            *(ushort8*)(dst + q8 * 8) = o;
        }
    }
    {   // vt: thread t -> (col d = t&127, 64-row segment seg = t>>7)
        int d = tid & 127, seg = tid >> 7;
        int bhn = b * NH + nb * 2 + (d >> 6);
        int dd = d & 63;
        ushort* dst = vt + ((size_t)bhn * HD + dd) * NTOK + nr0 + seg * 64;
        #pragma unroll
        for (int q8 = 0; q8 < 8; ++q8) {
            ushort8 o;
            #pragma unroll
            for (int j = 0; j < 8; ++j)
                o[j] = f2bf(Ct[(seg * 64 + q8 * 8 + j) * 132 + d]);
            *(ushort8*)(dst + q8 * 8) = o;
        }
    }
}

// ---------------------------------------------------------------------------
// Fallback fp32 vproj (used only if ws_size can't hold the split arrays).
// ---------------------------------------------------------------------------
__global__ __launch_bounds__(256) void vproj_fp32_kernel(
    const float* __restrict__ q, const float* __restrict__ w,
    ushort* __restrict__ vn, ushort* __restrict__ vt)
{
    __shared__ __align__(16) char smem[2 * 32 * 65 * 4];
    float (*As)[65] = (float (*)[65])smem;
    float (*Bs)[65] = (float (*)[65])(smem + 32 * 65 * 4);
    const int h = blockIdx.x, mb = blockIdx.y;
    const int tid = threadIdx.x;
    const int tx = tid & 15, ty = tid >> 4;
    const int m0 = mb * 64, b = m0 >> 10;
    const int lk = tid & 31, lr = tid >> 5;
    float acc[4][4] = {};
    for (int kt = 0; kt < DM; kt += 32) {
        #pragma unroll
        for (int p = 0; p < 8; ++p) {
            int row = lr + p * 8;
            int n = (m0 + row) & (NTOK - 1);
            As[lk][row] = q[(size_t)(n * BATCH + b) * DM + kt + lk];
            Bs[lk][row] = w[(size_t)(h * HD + row) * DM + kt + lk];
        }
        __syncthreads();
        #pragma unroll 8
        for (int k = 0; k < 32; ++k) {
            float a0 = As[k][4*ty+0], a1 = As[k][4*ty+1];
            float a2 = As[k][4*ty+2], a3 = As[k][4*ty+3];
            float b0 = Bs[k][4*tx+0], b1 = Bs[k][4*tx+1];
            float b2 = Bs[k][4*tx+2], b3 = Bs[k][4*tx+3];
            acc[0][0]+=a0*b0; acc[0][1]+=a0*b1; acc[0][2]+=a0*b2; acc[0][3]+=a0*b3;
            acc[1][0]+=a1*b0; acc[1][1]+=a1*b1; acc[1][2]+=a1*b2; acc[1][3]+=a1*b3;
            acc[2][0]+=a2*b0; acc[2][1]+=a2*b1; acc[2][2]+=a2*b2; acc[2][3]+=a2*b3;
            acc[3][0]+=a3*b0; acc[3][1]+=a3*b1; acc[3][2]+=a3*b2; acc[3][3]+=a3*b3;
        }
        __syncthreads();
    }
    const int bh = b * NH + h;
    const int n0 = m0 & (NTOK - 1);
    #pragma unroll
    for (int i = 0; i < 4; ++i) {
        float ss = acc[i][0]*acc[i][0] + acc[i][1]*acc[i][1]
                 + acc[i][2]*acc[i][2] + acc[i][3]*acc[i][3];
        #pragma unroll
        for (int msk = 1; msk < 16; msk <<= 1) ss += __shfl_xor(ss, msk, 16);
        float rn = rsqrtf(ss) * SQRT_CS;
        int n = n0 + 4*ty + i;
        ushort4 o;
        o.x = f2bf(acc[i][0]*rn); o.y = f2bf(acc[i][1]*rn);
        o.z = f2bf(acc[i][2]*rn); o.w = f2bf(acc[i][3]*rn);
        *(ushort4*)&vn[((size_t)bh * NTOK + n) * HD + 4*tx] = o;
    }
    ushort (*T)[72] = (ushort (*)[72])smem;
    #pragma unroll
    for (int i = 0; i < 4; ++i)
        #pragma unroll
        for (int j = 0; j < 4; ++j)
            T[4*tx + j][4*ty + i] = f2bf(acc[i][j]);
    __syncthreads();
    {
        int d = tid >> 2, c = tid & 3;
        uint4 lo = *(const uint4*)&T[d][c*16];
        uint4 hi = *(const uint4*)&T[d][c*16 + 8];
        size_t go = ((size_t)bh * HD + d) * NTOK + n0 + c*16;
        *(uint4*)&vt[go]     = lo;
        *(uint4*)&vt[go + 8] = hi;
    }
}

// ---------------------------------------------------------------------------
// Kernel 2: flash attention, round-10 structure (4 waves, Q-tile 128, dbuf
// K/V LDS, one barrier/tile) with GROUP-PIPELINED softmax/PV: QK fills both
// S-groups, then per group {exp2, sum, pack, PV} — group 1's VALU/trans work
// is independent of group 0's PV MFMAs so the scheduler can overlap them.
// setprio fences removed. vn pre-scaled: p = exp2(s) directly.
// ---------------------------------------------------------------------------
__global__ __launch_bounds__(256) void attn_kernel(
    const ushort* __restrict__ vn, const ushort* __restrict__ vt,
    float* __restrict__ out)
{
    __shared__ __align__(16) ushort Klds[2][64 * 64];   // [kv][d], swizzled
    __shared__ __align__(16) ushort Vlds[2][64 * 64];   // [d][kv], swizzled
    const int sblk = blockIdx.x;                 // 0..767
    const int tt   = sblk >> 3;
    const int bh   = (sblk & 7) + 8 * (tt >> 3); // XCD(bid%8) == bh%8
    const int q0   = (tt & 7) * 128;
    const int tid = threadIdx.x;
    const int wv  = tid >> 6;
    const int l   = tid & 63;
    const int ql  = l & 31;          // q column (one q-row per lane)
    const int h   = l >> 5;          // half

    const ushort* vb  = vn + (size_t)bh * NTOK * HD;
    const ushort* vtb = vt + (size_t)bh * HD * NTOK;

    short8 qB[4];
    {
        int qrow = q0 + wv * 32 + ql;
        #pragma unroll
        for (int ks = 0; ks < 4; ++ks)
            qB[ks] = *(const short8*)(vb + (size_t)qrow * HD + ks * 16 + h * 8);
    }

    const int sr0 = tid >> 3, sr1 = sr0 + 32;
    const int sc  = tid & 7;
    const int slt = (sc ^ (sr0 & 7)) * 8;        // sr1&7 == sr0&7
    uint4 kreg0, kreg1, vreg0, vreg1;

    f32x16 oT[2] = {};
    float l_acc = 0.f;

    kreg0 = *(const uint4*)(vb + (size_t)sr0 * HD + sc * 8);
    kreg1 = *(const uint4*)(vb + (size_t)sr1 * HD + sc * 8);
    vreg0 = *(const uint4*)(vtb + (size_t)sr0 * NTOK + sc * 8);
    vreg1 = *(const uint4*)(vtb + (size_t)sr1 * NTOK + sc * 8);
    *(uint4*)(&Klds[0][0] + sr0 * 64 + slt) = kreg0;
    *(uint4*)(&Klds[0][0] + sr1 * 64 + slt) = kreg1;
    *(uint4*)(&Vlds[0][0] + sr0 * 64 + slt) = vreg0;
    *(uint4*)(&Vlds[0][0] + sr1 * 64 + slt) = vreg1;
    __syncthreads();

    for (int kt = 0; kt < NTOK / 64; ++kt) {
        const int cur = kt & 1;
        const ushort* Kb = &Klds[cur][0];
        const ushort* Vb = &Vlds[cur][0];

        // T14: issue next tile's global loads early (land during compute)
        if (kt < NTOK / 64 - 1) {
            int kb = (kt + 1) * 64;
            kreg0 = *(const uint4*)(vb + (size_t)(kb + sr0) * HD + sc * 8);
            kreg1 = *(const uint4*)(vb + (size_t)(kb + sr1) * HD + sc * 8);
            vreg0 = *(const uint4*)(vtb + (size_t)sr0 * NTOK + kb + sc * 8);
            vreg1 = *(const uint4*)(vtb + (size_t)sr1 * NTOK + kb + sc * 8);
        }

        // QK^T: both 32-kv groups (chains interleave freely)
        f32x16 st[2] = {};
        #pragma unroll
        for (int ks = 0; ks < 4; ++ks) {
            int so = ((2 * ks + h) ^ (ql & 7)) * 8;
            short8 k0 = *(const short8*)(Kb + ql * 64 + so);
            short8 k1 = *(const short8*)(Kb + (32 + ql) * 64 + so);
            st[0] = mfma32(k0, qB[ks], st[0]);
            st[1] = mfma32(k1, qB[ks], st[1]);
        }

        // per group: exp2 -> sum -> pack -> PV  (group 1's VALU overlaps
        // group 0's PV MFMAs; no setprio fences)
        #pragma unroll
        for (int g = 0; g < 2; ++g) {
            #pragma unroll
            for (int i = 0; i < 16; ++i)
                st[g][i] = __builtin_amdgcn_exp2f(st[g][i]);

            float ts[8];
            #pragma unroll
            for (int i = 0; i < 8; ++i) ts[i] = st[g][i] + st[g][i + 8];
            #pragma unroll
            for (int s = 4; s >= 1; s >>= 1)
                #pragma unroll
                for (int i = 0; i < s; ++i) ts[i] += ts[i + s];
            l_acc += ts[0];

            unsigned pb2[4][2];
            #pragma unroll
            for (int t = 0; t < 4; ++t)
                #pragma unroll
                for (int u = 0; u < 2; ++u)
                    asm("v_cvt_pk_bf16_f32 %0, %1, %2"
                        : "=v"(pb2[t][u])
                        : "v"(st[g][4 * t + 2 * u]), "v"(st[g][4 * t + 2 * u + 1]));

            #pragma unroll
            for (int sp = 0; sp < 2; ++sp) {
                const int s = g * 2 + sp;
                unsigned x0 = pb2[2 * sp][0], y0 = pb2[2 * sp + 1][0];
                unsigned x1 = pb2[2 * sp][1], y1 = pb2[2 * sp + 1][1];
                asm volatile("v_permlane32_swap_b32 %0, %1" : "+v"(x0), "+v"(y0));
                asm volatile("v_permlane32_swap_b32 %0, %1" : "+v"(x1), "+v"(y1));
                union { unsigned u[4]; short8 s8; } pb;
                pb.u[0] = x0; pb.u[1] = x1; pb.u[2] = y0; pb.u[3] = y1;
                int so = ((2 * s + h) ^ (ql & 7)) * 8;
                short8 v0 = *(const short8*)(Vb + ql * 64 + so);
                short8 v1 = *(const short8*)(Vb + (32 + ql) * 64 + so);
                oT[0] = mfma32(v0, pb.s8, oT[0]);
                oT[1] = mfma32(v1, pb.s8, oT[1]);
            }
        }

        __syncthreads();                 // all waves done reading tile kt
        if (kt < NTOK / 64 - 1) {
            *(uint4*)(&Klds[cur ^ 1][0] + sr0 * 64 + slt) = kreg0;
            *(uint4*)(&Klds[cur ^ 1][0] + sr1 * 64 + slt) = kreg1;
            *(uint4*)(&Vlds[cur ^ 1][0] + sr0 * 64 + slt) = vreg0;
            *(uint4*)(&Vlds[cur ^ 1][0] + sr1 * 64 + slt) = vreg1;
            __syncthreads();
        }
    }

    const int b = bh / NH, hh = bh % NH;
    float lsum = l_acc + __shfl_xor(l_acc, 32);
    const float inv = 1.f / lsum;
    int n = q0 + wv * 32 + ql;
    float* orow = out + ((size_t)n * BATCH + b) * DM + hh * HD;
    #pragma unroll
    for (int dm = 0; dm < 2; ++dm)
        #pragma unroll
        for (int t = 0; t < 4; ++t) {
            float4 val = make_float4(oT[dm][4 * t] * inv, oT[dm][4 * t + 1] * inv,
                                     oT[dm][4 * t + 2] * inv, oT[dm][4 * t + 3] * inv);
            *(float4*)(orow + dm * 32 + t * 8 + h * 4) = val;
        }
}

extern "C" void kernel_launch(void* const* d_in, const int* in_sizes, int n_in,
                              void* d_out, int out_size, void* d_ws, size_t ws_size,
                              hipStream_t stream) {
    const float* q = (const float*)d_in[0];   // [1024, 8, 768]
    const float* w = (const float*)d_in[1];   // [768, 768]
    float* out = (float*)d_out;               // [1024, 8, 768]

    const size_t QE = (size_t)NTOK * BATCH * DM;     // 6,291,456
    const size_t WE = (size_t)DM * DM;               //   589,824
    const size_t VE = (size_t)NH * BATCH * NTOK * HD;// 6,291,456

    ushort* vn = (ushort*)d_ws;
    ushort* vt = vn + VE;
    size_t need = (2 * VE + 2 * QE + 2 * WE) * sizeof(ushort);

    if (ws_size >= need) {
        ushort* qh = vt + VE;
        ushort* ql = qh + QE;
        ushort* wh = ql + QE;
        ushort* wl = wh + WE;
        int nsplit = (int)((QE / 8 + WE / 8 + 255) / 256);
        split_qw_kernel<<<nsplit, 256, 0, stream>>>(q, w, qh, ql, wh, wl);
        vproj_mfma_kernel<<<384, 256, 0, stream>>>(qh, ql, wh, wl, vn, vt);
    } else {
        vproj_fp32_kernel<<<dim3(NH, (BATCH * NTOK) / 64), 256, 0, stream>>>(q, w, vn, vt);
    }
    attn_kernel<<<NTOK / 128 * BATCH * NH, 256, 0, stream>>>(vn, vt, out);
}